// Round 3
// baseline (1407.399 us; speedup 1.0000x reference)
//
#include <hip/hip_runtime.h>
#include <hip/hip_bf16.h>
#include <stdint.h>
#include <math.h>

#define NIN_  512
#define NOUT_ 128
#define CIN_  128
#define COUT_ 32
#define MO_   4096   // NOUT*COUT

typedef __attribute__((ext_vector_type(4))) float f32x4;

// ---------------------------------------------------------------------------
// K1 (fp32): u[n][bl][mo] = sum_c W1[n][mo][c] * x[b0+bl][n][c]
// grid = 512 n * 16 mo-tiles(256); block 256 = 4 waves.
// W staged in LDS as XOR-swizzled float4 units (conflict-free b128).
// (unchanged from round 2 — near BW-bound)
// ---------------------------------------------------------------------------
__global__ __launch_bounds__(256) void k_build(const float* __restrict__ x,
                                               const float* __restrict__ W1,
                                               float* __restrict__ u,
                                               int NB, int b0) {
    const int n   = blockIdx.x >> 4;
    const int mt  = blockIdx.x & 15;
    const int mo0 = mt * 256;
    const int t   = threadIdx.x;
    const int l   = t & 63;
    const int bg  = t >> 6;

    __shared__ f32x4 xs4[32 * 32];   // [bl][cu]  16 KB
    __shared__ f32x4 ws4[256 * 8];   // swizzled   32 KB

    const int nxu = NB * 32;
    for (int k = t; k < nxu; k += 256) {
        const int bl = k >> 5;
        const int cu = k & 31;
        xs4[k] = *(const f32x4*)(x + (((size_t)(b0 + bl) * NIN_ + n) * CIN_ + cu * 4));
    }

    const int cu8 = t & 7;
    const int row = t >> 3;
    const int active = (bg < (NB >> 3));

    float acc[4][8];
#pragma unroll
    for (int i = 0; i < 4; ++i)
#pragma unroll
        for (int j = 0; j < 8; ++j) acc[i][j] = 0.f;

    f32x4 wr[8];
#pragma unroll
    for (int p = 0; p < 8; ++p) {
        const int ml = row + p * 32;
        wr[p] = *(const f32x4*)(W1 + ((size_t)(n * MO_ + mo0 + ml) * CIN_ + 0 * 32 + cu8 * 4));
    }

    for (int ch = 0; ch < 4; ++ch) {
        __syncthreads();
#pragma unroll
        for (int p = 0; p < 8; ++p) {
            const int ml = row + p * 32;
            ws4[ml * 8 + (cu8 ^ (ml & 7))] = wr[p];
        }
        __syncthreads();
        if (ch < 3) {
#pragma unroll
            for (int p = 0; p < 8; ++p) {
                const int ml = row + p * 32;
                wr[p] = *(const f32x4*)(W1 + ((size_t)(n * MO_ + mo0 + ml) * CIN_ + (ch + 1) * 32 + cu8 * 4));
            }
        }
        if (active) {
#pragma unroll
            for (int c4 = 0; c4 < 8; ++c4) {
                f32x4 wv[4];
#pragma unroll
                for (int i = 0; i < 4; ++i)
                    wv[i] = ws4[(l + i * 64) * 8 + (c4 ^ (l & 7))];
                f32x4 xq[8];
#pragma unroll
                for (int j = 0; j < 8; ++j)
                    xq[j] = xs4[(bg * 8 + j) * 32 + ch * 8 + c4];
#pragma unroll
                for (int i = 0; i < 4; ++i)
#pragma unroll
                    for (int j = 0; j < 8; ++j) {
                        acc[i][j] += wv[i][0] * xq[j][0];
                        acc[i][j] += wv[i][1] * xq[j][1];
                        acc[i][j] += wv[i][2] * xq[j][2];
                        acc[i][j] += wv[i][3] * xq[j][3];
                    }
            }
        }
    }

    if (active) {
#pragma unroll
        for (int i = 0; i < 4; ++i)
#pragma unroll
            for (int j = 0; j < 8; ++j)
                u[((size_t)n * NB + bg * 8 + j) * MO_ + mo0 + i * 64 + l] = acc[i][j];
    }
}

// ---------------------------------------------------------------------------
// Route compute step for one n — math identical to round 2 (bit-exact).
// ---------------------------------------------------------------------------
template<int MODE>
static __device__ __forceinline__ void route_step(const f32x4 (&ur)[16],
                                                  const f32x4 (&vr)[16],
                                                  f32x4 (&sacc)[16],
                                                  float* __restrict__ blog,
                                                  int n, int bl, int sub, int l) {
    if (MODE == 0) {
        const float cu = 1.0f / 128.0f;
#pragma unroll
        for (int j = 0; j < 16; ++j) {
            sacc[j][0] += cu * ur[j][0]; sacc[j][1] += cu * ur[j][1];
            sacc[j][2] += cu * ur[j][2]; sacc[j][3] += cu * ur[j][3];
        }
    } else {
        float* bp = blog + ((size_t)bl * NIN_ + n) * NOUT_;
        float bn[16];
        float mx = -1e30f;
#pragma unroll
        for (int j = 0; j < 16; ++j) {
            float p = vr[j][0] * ur[j][0] + vr[j][1] * ur[j][1]
                    + vr[j][2] * ur[j][2] + vr[j][3] * ur[j][3];
            p += __shfl_xor(p, 1, 64);
            p += __shfl_xor(p, 2, 64);
            p += __shfl_xor(p, 4, 64);
            const float old = (MODE == 1) ? 0.f : bp[j * 8 + sub];
            bn[j] = old + p;
            mx = fmaxf(mx, bn[j]);
        }
        if ((l & 7) == 0) {
#pragma unroll
            for (int j = 0; j < 16; ++j) bp[j * 8 + sub] = bn[j];
        }
        mx = fmaxf(mx, __shfl_xor(mx, 8, 64));
        mx = fmaxf(mx, __shfl_xor(mx, 16, 64));
        mx = fmaxf(mx, __shfl_xor(mx, 32, 64));
        float se = 0.f;
#pragma unroll
        for (int j = 0; j < 16; ++j) {
            bn[j] = expf(bn[j] - mx);
            se += bn[j];
        }
        se += __shfl_xor(se, 8, 64);
        se += __shfl_xor(se, 16, 64);
        se += __shfl_xor(se, 32, 64);
        const float inv = 1.0f / se;
#pragma unroll
        for (int j = 0; j < 16; ++j) {
            const float c = bn[j] * inv;
            sacc[j][0] += c * ur[j][0]; sacc[j][1] += c * ur[j][1];
            sacc[j][2] += c * ur[j][2]; sacc[j][3] += c * ur[j][3];
        }
    }
}

// ---------------------------------------------------------------------------
// K2 fused routing iteration (fp32), software-pipelined u prefetch (urA/urB).
// MODE: 0 = uniform c, 1 = first agree (blog=0), 2 = normal
// grid = (NB/4)*32; block 256 = 4 waves; wave -> bl, block -> 16-n chunk q.
// ---------------------------------------------------------------------------
template<int MODE>
__global__ __launch_bounds__(256, 1) void k_route(const float* __restrict__ u,
                                                  const float* __restrict__ vws,
                                                  float* __restrict__ blog,
                                                  float* __restrict__ spart,
                                                  int NB) {
    const int nbg = NB >> 2;
    const int bg  = blockIdx.x % nbg;
    const int q   = blockIdx.x / nbg;   // 0..31
    const int w   = threadIdx.x >> 6;
    const int l   = threadIdx.x & 63;
    const int bl  = bg * 4 + w;
    const int sub = l >> 3;

    f32x4 vr[16];
    if (MODE != 0) {
#pragma unroll
        for (int j = 0; j < 16; ++j)
            vr[j] = *(const f32x4*)(vws + (size_t)bl * MO_ + (j * 64 + l) * 4);
    }

    f32x4 sacc[16];
#pragma unroll
    for (int j = 0; j < 16; ++j) sacc[j] = (f32x4){0.f, 0.f, 0.f, 0.f};

    const int n0 = q * 16;
    f32x4 urA[16], urB[16];
    {
        const f32x4* up = (const f32x4*)(u + ((size_t)n0 * NB + bl) * MO_);
#pragma unroll
        for (int j = 0; j < 16; ++j) urA[j] = up[j * 64 + l];
    }

    for (int nn = 0; nn < 16; nn += 2) {
        {   // prefetch n = n0+nn+1 into urB while computing urA
            const f32x4* up = (const f32x4*)(u + ((size_t)(n0 + nn + 1) * NB + bl) * MO_);
#pragma unroll
            for (int j = 0; j < 16; ++j) urB[j] = up[j * 64 + l];
        }
        route_step<MODE>(urA, vr, sacc, blog, n0 + nn, bl, sub, l);
        if (nn + 2 < 16) {   // prefetch n = n0+nn+2 into urA while computing urB
            const f32x4* up = (const f32x4*)(u + ((size_t)(n0 + nn + 2) * NB + bl) * MO_);
#pragma unroll
            for (int j = 0; j < 16; ++j) urA[j] = up[j * 64 + l];
        }
        route_step<MODE>(urB, vr, sacc, blog, n0 + nn + 1, bl, sub, l);
    }

    f32x4* sp = (f32x4*)(spart + ((size_t)q * NB + bl) * MO_);
#pragma unroll
    for (int j = 0; j < 16; ++j) sp[j * 64 + l] = sacc[j];
}

// ---------------------------------------------------------------------------
// K3: s = sum_q spart; v = |s|*s/(0.5+s^2) -> vws      (mid iterations)
// ---------------------------------------------------------------------------
__global__ __launch_bounds__(256) void k_squash_mid(const float* __restrict__ spart,
                                                    float* __restrict__ vws, int NB) {
    const int j = blockIdx.x * 256 + threadIdx.x;
    const size_t stride = (size_t)NB * MO_;
    float s = 0.f;
#pragma unroll
    for (int q = 0; q < 32; ++q) s += spart[q * stride + j];
    const float s2 = s * s;
    vws[j] = (sqrtf(s2) / (0.5f + s2)) * s;
}

// ---------------------------------------------------------------------------
// K4: final squash -> poses (fp32, [b][m][o]) + activations [b][m]
// ---------------------------------------------------------------------------
__global__ __launch_bounds__(256) void k_squash_fin(const float* __restrict__ spart,
                                                    float* __restrict__ out,
                                                    int NB, int b0) {
    const int j = blockIdx.x * 256 + threadIdx.x;
    const size_t stride = (size_t)NB * MO_;
    float s = 0.f;
#pragma unroll
    for (int q = 0; q < 32; ++q) s += spart[q * stride + j];
    const float s2 = s * s;
    const float v = (sqrtf(s2) / (0.5f + s2)) * s;
    out[(size_t)b0 * MO_ + j] = v;

    float v2 = v * v;
#pragma unroll
    for (int d = 16; d >= 1; d >>= 1) v2 += __shfl_xor(v2, d, 64);
    if ((j & 31) == 0) {
        const int bl = j >> 12;
        const int m  = (j >> 5) & 127;
        out[131072 + (size_t)(b0 + bl) * NOUT_ + m] = sqrtf(v2);
    }
}

// ---------------------------------------------------------------------------
extern "C" void kernel_launch(void* const* d_in, const int* in_sizes, int n_in,
                              void* d_out, int out_size, void* d_ws, size_t ws_size,
                              hipStream_t stream) {
    const float* x  = (const float*)d_in[0];
    const float* W1 = (const float*)d_in[1];
    float* out = (float*)d_out;

    const size_t need32 = (size_t)32 * NIN_ * MO_ * 4
                        + (size_t)32 * NIN_ * NOUT_ * 4
                        + (size_t)32 * MO_ * 4
                        + (size_t)32 * 32 * MO_ * 4;
    const int NB = (ws_size >= need32) ? 32 : 16;
    const int npass = 32 / NB;

    char* ws = (char*)d_ws;
    const size_t bytes_u  = (size_t)NB * NIN_ * MO_ * 4;
    const size_t bytes_bl = (size_t)NB * NIN_ * NOUT_ * 4;
    const size_t bytes_v  = (size_t)NB * MO_ * 4;
    float* u     = (float*)(ws);
    float* blog  = (float*)(ws + bytes_u);
    float* vws   = (float*)(ws + bytes_u + bytes_bl);
    float* spart = (float*)(ws + bytes_u + bytes_bl + bytes_v);

    const int rgrid = (NB / 4) * 32;

    for (int pass = 0; pass < npass; ++pass) {
        const int b0 = pass * NB;

        k_build<<<8192, 256, 0, stream>>>(x, W1, u, NB, b0);

        // iteration 1: uniform c
        k_route<0><<<rgrid, 256, 0, stream>>>(u, vws, blog, spart, NB);
        k_squash_mid<<<NB * 16, 256, 0, stream>>>(spart, vws, NB);

        for (int it = 1; it <= 9; ++it) {
            if (it == 1) k_route<1><<<rgrid, 256, 0, stream>>>(u, vws, blog, spart, NB);
            else         k_route<2><<<rgrid, 256, 0, stream>>>(u, vws, blog, spart, NB);
            if (it < 9) k_squash_mid<<<NB * 16, 256, 0, stream>>>(spart, vws, NB);
            else        k_squash_fin<<<NB * 16, 256, 0, stream>>>(spart, out, NB, b0);
        }
    }
}

// Round 4
// 1136.468 us; speedup vs baseline: 1.2384x; 1.2384x over previous
//
#include <hip/hip_runtime.h>
#include <hip/hip_bf16.h>
#include <stdint.h>
#include <math.h>

#define NIN_  512
#define NOUT_ 128
#define CIN_  128
#define COUT_ 32
#define MO_   4096   // NOUT*COUT
#define NQ_   64     // n-chunks for route (8 n each)

typedef __attribute__((ext_vector_type(4))) float f32x4;

// ---------------------------------------------------------------------------
// K1 (fp32): u[n][bl][mo] = sum_c W1[n][mo][c] * x[b0+bl][n][c]
// grid = 512 n * 16 mo-tiles(256); block 256 = 4 waves.
// W staged in LDS as XOR-swizzled float4 units (conflict-free b128).
// (unchanged — near BW-bound)
// ---------------------------------------------------------------------------
__global__ __launch_bounds__(256) void k_build(const float* __restrict__ x,
                                               const float* __restrict__ W1,
                                               float* __restrict__ u,
                                               int NB, int b0) {
    const int n   = blockIdx.x >> 4;
    const int mt  = blockIdx.x & 15;
    const int mo0 = mt * 256;
    const int t   = threadIdx.x;
    const int l   = t & 63;
    const int bg  = t >> 6;

    __shared__ f32x4 xs4[32 * 32];   // [bl][cu]  16 KB
    __shared__ f32x4 ws4[256 * 8];   // swizzled   32 KB

    const int nxu = NB * 32;
    for (int k = t; k < nxu; k += 256) {
        const int bl = k >> 5;
        const int cu = k & 31;
        xs4[k] = *(const f32x4*)(x + (((size_t)(b0 + bl) * NIN_ + n) * CIN_ + cu * 4));
    }

    const int cu8 = t & 7;
    const int row = t >> 3;
    const int active = (bg < (NB >> 3));

    float acc[4][8];
#pragma unroll
    for (int i = 0; i < 4; ++i)
#pragma unroll
        for (int j = 0; j < 8; ++j) acc[i][j] = 0.f;

    f32x4 wr[8];
#pragma unroll
    for (int p = 0; p < 8; ++p) {
        const int ml = row + p * 32;
        wr[p] = *(const f32x4*)(W1 + ((size_t)(n * MO_ + mo0 + ml) * CIN_ + 0 * 32 + cu8 * 4));
    }

    for (int ch = 0; ch < 4; ++ch) {
        __syncthreads();
#pragma unroll
        for (int p = 0; p < 8; ++p) {
            const int ml = row + p * 32;
            ws4[ml * 8 + (cu8 ^ (ml & 7))] = wr[p];
        }
        __syncthreads();
        if (ch < 3) {
#pragma unroll
            for (int p = 0; p < 8; ++p) {
                const int ml = row + p * 32;
                wr[p] = *(const f32x4*)(W1 + ((size_t)(n * MO_ + mo0 + ml) * CIN_ + (ch + 1) * 32 + cu8 * 4));
            }
        }
        if (active) {
#pragma unroll
            for (int c4 = 0; c4 < 8; ++c4) {
                f32x4 wv[4];
#pragma unroll
                for (int i = 0; i < 4; ++i)
                    wv[i] = ws4[(l + i * 64) * 8 + (c4 ^ (l & 7))];
                f32x4 xq[8];
#pragma unroll
                for (int j = 0; j < 8; ++j)
                    xq[j] = xs4[(bg * 8 + j) * 32 + ch * 8 + c4];
#pragma unroll
                for (int i = 0; i < 4; ++i)
#pragma unroll
                    for (int j = 0; j < 8; ++j) {
                        acc[i][j] += wv[i][0] * xq[j][0];
                        acc[i][j] += wv[i][1] * xq[j][1];
                        acc[i][j] += wv[i][2] * xq[j][2];
                        acc[i][j] += wv[i][3] * xq[j][3];
                    }
            }
        }
    }

    if (active) {
#pragma unroll
        for (int i = 0; i < 4; ++i)
#pragma unroll
            for (int j = 0; j < 8; ++j)
                u[((size_t)n * NB + bg * 8 + j) * MO_ + mo0 + i * 64 + l] = acc[i][j];
    }
}

// ---------------------------------------------------------------------------
// K2 fused routing iteration (fp32) — round-2 body, more n-parallelism.
// MODE: 0 = uniform c, 1 = first agree (blog=0), 2 = normal
// grid = (NB/4)*NQ_; block 256 = 4 waves; wave -> bl; block -> 8-n chunk q.
// Lane layout: float4 unit f = j*64+l; m = j*8 + (l>>3); o = (l&7)*4 + i.
// ---------------------------------------------------------------------------
template<int MODE>
__global__ __launch_bounds__(256) void k_route(const float* __restrict__ u,
                                               const float* __restrict__ vws,
                                               float* __restrict__ blog,
                                               float* __restrict__ spart,
                                               int NB) {
    const int nbg = NB >> 2;
    const int bg  = blockIdx.x % nbg;
    const int q   = blockIdx.x / nbg;   // 0..NQ_-1
    const int w   = threadIdx.x >> 6;
    const int l   = threadIdx.x & 63;
    const int bl  = bg * 4 + w;
    const int sub = l >> 3;

    f32x4 vr[16];
    if (MODE != 0) {
#pragma unroll
        for (int j = 0; j < 16; ++j)
            vr[j] = *(const f32x4*)(vws + (size_t)bl * MO_ + (j * 64 + l) * 4);
    }

    f32x4 sacc[16];
#pragma unroll
    for (int j = 0; j < 16; ++j) sacc[j] = (f32x4){0.f, 0.f, 0.f, 0.f};

    for (int nn = 0; nn < 8; ++nn) {
        const int n = q * 8 + nn;
        const f32x4* up = (const f32x4*)(u + ((size_t)n * NB + bl) * MO_);
        f32x4 ur[16];
#pragma unroll
        for (int j = 0; j < 16; ++j) ur[j] = up[j * 64 + l];

        if (MODE == 0) {
            const float cu = 1.0f / 128.0f;
#pragma unroll
            for (int j = 0; j < 16; ++j) {
                sacc[j][0] += cu * ur[j][0]; sacc[j][1] += cu * ur[j][1];
                sacc[j][2] += cu * ur[j][2]; sacc[j][3] += cu * ur[j][3];
            }
        } else {
            float* bp = blog + ((size_t)bl * NIN_ + n) * NOUT_;
            float bn[16];
            float mx = -1e30f;
#pragma unroll
            for (int j = 0; j < 16; ++j) {
                float p = vr[j][0] * ur[j][0] + vr[j][1] * ur[j][1]
                        + vr[j][2] * ur[j][2] + vr[j][3] * ur[j][3];
                p += __shfl_xor(p, 1, 64);
                p += __shfl_xor(p, 2, 64);
                p += __shfl_xor(p, 4, 64);
                const float old = (MODE == 1) ? 0.f : bp[j * 8 + sub];
                bn[j] = old + p;
                mx = fmaxf(mx, bn[j]);
            }
            if ((l & 7) == 0) {
#pragma unroll
                for (int j = 0; j < 16; ++j) bp[j * 8 + sub] = bn[j];
            }
            mx = fmaxf(mx, __shfl_xor(mx, 8, 64));
            mx = fmaxf(mx, __shfl_xor(mx, 16, 64));
            mx = fmaxf(mx, __shfl_xor(mx, 32, 64));
            float se = 0.f;
#pragma unroll
            for (int j = 0; j < 16; ++j) {
                bn[j] = expf(bn[j] - mx);
                se += bn[j];
            }
            se += __shfl_xor(se, 8, 64);
            se += __shfl_xor(se, 16, 64);
            se += __shfl_xor(se, 32, 64);
            const float inv = 1.0f / se;
#pragma unroll
            for (int j = 0; j < 16; ++j) {
                const float c = bn[j] * inv;
                sacc[j][0] += c * ur[j][0]; sacc[j][1] += c * ur[j][1];
                sacc[j][2] += c * ur[j][2]; sacc[j][3] += c * ur[j][3];
            }
        }
    }

    f32x4* sp = (f32x4*)(spart + ((size_t)q * NB + bl) * MO_);
#pragma unroll
    for (int j = 0; j < 16; ++j) sp[j * 64 + l] = sacc[j];
}

// ---------------------------------------------------------------------------
// K3: s = sum_q spart; v = |s|*s/(0.5+s^2) -> vws      (mid iterations)
// ---------------------------------------------------------------------------
__global__ __launch_bounds__(256) void k_squash_mid(const float* __restrict__ spart,
                                                    float* __restrict__ vws, int NB) {
    const int j = blockIdx.x * 256 + threadIdx.x;
    const size_t stride = (size_t)NB * MO_;
    float s = 0.f;
#pragma unroll
    for (int q = 0; q < NQ_; ++q) s += spart[q * stride + j];
    const float s2 = s * s;
    vws[j] = (sqrtf(s2) / (0.5f + s2)) * s;
}

// ---------------------------------------------------------------------------
// K4: final squash -> poses (fp32, [b][m][o]) + activations [b][m]
// ---------------------------------------------------------------------------
__global__ __launch_bounds__(256) void k_squash_fin(const float* __restrict__ spart,
                                                    float* __restrict__ out,
                                                    int NB, int b0) {
    const int j = blockIdx.x * 256 + threadIdx.x;
    const size_t stride = (size_t)NB * MO_;
    float s = 0.f;
#pragma unroll
    for (int q = 0; q < NQ_; ++q) s += spart[q * stride + j];
    const float s2 = s * s;
    const float v = (sqrtf(s2) / (0.5f + s2)) * s;
    out[(size_t)b0 * MO_ + j] = v;

    float v2 = v * v;
#pragma unroll
    for (int d = 16; d >= 1; d >>= 1) v2 += __shfl_xor(v2, d, 64);
    if ((j & 31) == 0) {
        const int bl = j >> 12;
        const int m  = (j >> 5) & 127;
        out[131072 + (size_t)(b0 + bl) * NOUT_ + m] = sqrtf(v2);
    }
}

// ---------------------------------------------------------------------------
extern "C" void kernel_launch(void* const* d_in, const int* in_sizes, int n_in,
                              void* d_out, int out_size, void* d_ws, size_t ws_size,
                              hipStream_t stream) {
    const float* x  = (const float*)d_in[0];
    const float* W1 = (const float*)d_in[1];
    float* out = (float*)d_out;

    const size_t need32 = (size_t)32 * NIN_ * MO_ * 4          // u
                        + (size_t)32 * NIN_ * NOUT_ * 4        // blog
                        + (size_t)32 * MO_ * 4                 // vws
                        + (size_t)NQ_ * 32 * MO_ * 4;          // spart
    const int NB = (ws_size >= need32) ? 32 : 16;
    const int npass = 32 / NB;

    char* ws = (char*)d_ws;
    const size_t bytes_u  = (size_t)NB * NIN_ * MO_ * 4;
    const size_t bytes_bl = (size_t)NB * NIN_ * NOUT_ * 4;
    const size_t bytes_v  = (size_t)NB * MO_ * 4;
    float* u     = (float*)(ws);
    float* blog  = (float*)(ws + bytes_u);
    float* vws   = (float*)(ws + bytes_u + bytes_bl);
    float* spart = (float*)(ws + bytes_u + bytes_bl + bytes_v);

    const int rgrid = (NB / 4) * NQ_;

    for (int pass = 0; pass < npass; ++pass) {
        const int b0 = pass * NB;

        k_build<<<8192, 256, 0, stream>>>(x, W1, u, NB, b0);

        // iteration 1: uniform c
        k_route<0><<<rgrid, 256, 0, stream>>>(u, vws, blog, spart, NB);
        k_squash_mid<<<NB * 16, 256, 0, stream>>>(spart, vws, NB);

        for (int it = 1; it <= 9; ++it) {
            if (it == 1) k_route<1><<<rgrid, 256, 0, stream>>>(u, vws, blog, spart, NB);
            else         k_route<2><<<rgrid, 256, 0, stream>>>(u, vws, blog, spart, NB);
            if (it < 9) k_squash_mid<<<NB * 16, 256, 0, stream>>>(spart, vws, NB);
            else        k_squash_fin<<<NB * 16, 256, 0, stream>>>(spart, out, NB, b0);
        }
    }
}